// Round 14
// baseline (18464.473 us; speedup 1.0000x reference)
//
#include <hip/hip_runtime.h>

#define SEQ 1024
#define ISZ 6
#define HSZ 128
#define PRED 50
#define M2   32            // rows per pair
#define NP   128           // pairs
#define HP   136           // h row pitch in shorts (272B)
#define XCH  8
#define NS   2
#define TSTEPS (SEQ + PRED)

// ---- d_ws layout (pipe mode). r12 timeout proved ws_size >= 4.4MB. ----
#define F_H0   ((size_t)0)
#define F_CUR  ((size_t)16384)
#define F_CONS ((size_t)32768)
#define F_ABT  ((size_t)49152)
#define FLAGBYTES ((size_t)49280)
#define R_H0   FLAGBYTES                              // NP*NS*8192 = 2MB
#define R_CUR  (R_H0 + (size_t)NP*NS*8192)            // NP*NS*512 = 128KB
#define R_W1   (R_CUR + (size_t)NP*NS*512)            // wih1 bf16 pack 128KB
#define WS_NEED (R_W1 + (size_t)131072)

using f32x4  = __attribute__((ext_vector_type(4))) float;
using bf16x8 = __attribute__((ext_vector_type(8))) short;

__device__ __forceinline__ short f2bf(float f){
  union { float f; unsigned u; } v; v.f = f;
  unsigned r = v.u + 0x7FFFu + ((v.u >> 16) & 1u);
  return (short)(r >> 16);
}
__device__ __forceinline__ float bf2f(unsigned short us){
  union { unsigned u; float f; } v; v.u = ((unsigned)us) << 16; return v.f;
}
__device__ __forceinline__ float sigf(float x){
  float e = __builtin_amdgcn_exp2f(x * -1.4426950408889634f);
  return __builtin_amdgcn_rcpf(1.0f + e);
}
__device__ __forceinline__ float tanhf_(float x){
  float e = __builtin_amdgcn_exp2f(x * 2.8853900817779268f);
  return 1.0f - 2.0f * __builtin_amdgcn_rcpf(1.0f + e);
}
#define PIN(v) asm volatile("" : "+v"(v))

__device__ __forceinline__ int aldf(const int* p){
  return __hip_atomic_load(p, __ATOMIC_ACQUIRE, __HIP_MEMORY_SCOPE_AGENT);
}
__device__ __forceinline__ void astf(int* p, int v){
  __hip_atomic_store(p, v, __ATOMIC_RELEASE, __HIP_MEMORY_SCOPE_AGENT);
}
__device__ __forceinline__ unsigned long long ald64(const void* p){
  return __hip_atomic_load((const unsigned long long*)p, __ATOMIC_RELAXED, __HIP_MEMORY_SCOPE_AGENT);
}
__device__ __forceinline__ void ast64(void* p, unsigned long long v){
  __hip_atomic_store((unsigned long long*)p, v, __ATOMIC_RELAXED, __HIP_MEMORY_SCOPE_AGENT);
}
// sticky-abort spin: hang -> ~0.2s abort -> garbage finish (fast absmax fail
// with counters), never a 600s timeout.
__device__ __forceinline__ void waitge(const int* f, int v, int* abt){
  if (threadIdx.x == 0){
    int n = 0;
    while (aldf(f) < v){
      if ((n & 63) == 0 && aldf(abt)) break;
      __builtin_amdgcn_s_sleep(8);
      if (++n > (1 << 20)){ astf(abt, 1); break; }
    }
  }
  __syncthreads();
}

// 256 blocks = 128 L0 + 128 L1, M=32 rows/pair. Capacity (2 blocks/CU by
// LDS<=30KB and VGPR<=128) = 512 slots >= 2x grid -> co-residency guaranteed
// with slack (r12's exact-fit 512-on-512 hung; r13's occupancy query lied).
__global__
__attribute__((amdgpu_flat_work_group_size(512, 512)))
void lstm_pipe(
    const float* __restrict__ x,
    const float* __restrict__ w_ih0, const float* __restrict__ w_hh0,
    const float* __restrict__ b_ih0, const float* __restrict__ b_hh0,
    const float* __restrict__ w_ih1, const float* __restrict__ w_hh1,
    const float* __restrict__ b_ih1, const float* __restrict__ b_hh1,
    const float* __restrict__ fc_w, const float* __restrict__ fc_b,
    float* __restrict__ out, char* __restrict__ ws)
{
  const int tid  = threadIdx.x;
  const int wv   = tid >> 6;
  const int lane = tid & 63;
  const int l15  = lane & 15;
  const int lq   = lane >> 4;
  const int u    = wv*16 + l15;          // hidden unit (8 waves x 16 = 128)
  const int type = (blockIdx.x >= NP) ? 1 : 0;
  const int p    = blockIdx.x & (NP-1);  // pair id; (p, NP+p) share an XCD
  const int row0 = p * M2;

  int* h0f      = (int*)(ws + F_H0   + (size_t)p*128);
  int* curf     = (int*)(ws + F_CUR  + (size_t)p*128);
  int* consf    = (int*)(ws + F_CONS + (size_t)p*128);
  int* abt      = (int*)(ws + F_ABT);
  char* h0ring  = ws + R_H0  + (size_t)p*(NS*8192);
  char* curring = ws + R_CUR + (size_t)p*(NS*512);
  short* w1p    = (short*)(ws + R_W1);

  if (type == 0){
    // ================= L0: layer 0, fully resident, no streaming ===========
    __shared__ __align__(16) short s_h0[2][M2*HP];   // 17408B
    __shared__ __align__(16) short s_x[XCH*M2*8];    // 4096B
    __shared__ __align__(16) short s_wih0[512*8];    // 8192B
    __shared__ __align__(16) short s_zp[8];

    for (int i = tid; i < 2*M2*HP; i += 512) (&s_h0[0][0])[i] = 0;
    for (int i = tid; i < XCH*M2*8; i += 512) s_x[i] = 0;
    if (tid < 8) s_zp[tid] = 0;
    {
      #pragma unroll
      for (int k = 0; k < 6; k++) s_wih0[tid*8 + k] = f2bf(w_ih0[tid*6 + k]);
      s_wih0[tid*8 + 6] = 0; s_wih0[tid*8 + 7] = 0;
    }
    bf16x8 whh0f[4][4];
    float bias0[4];
    #pragma unroll
    for (int g = 0; g < 4; g++){
      const int c = g*128 + u;
      bias0[g] = b_ih0[c] + b_hh0[c];
      #pragma unroll
      for (int kt = 0; kt < 4; kt++){
        const float* wp = w_hh0 + c*HSZ + kt*32 + lq*8;
        bf16x8 f;
        #pragma unroll
        for (int i = 0; i < 8; i++) f[i] = f2bf(wp[i]);
        whh0f[g][kt] = f;
      }
    }
    float c0[2][4] = {{0.f,0.f,0.f,0.f},{0.f,0.f,0.f,0.f}};
    __syncthreads();

    for (int t = 0; t < TSTEPS; ++t){
      #pragma unroll
      for (int g = 0; g < 4; g++){
        #pragma unroll
        for (int kt = 0; kt < 4; kt++) PIN(whh0f[g][kt]);
      }
      if (t >= NS) waitge(consf, t - NS + 1, abt);   // ring credit

      if (t < SEQ && (t & (XCH-1)) == 0){
        for (int i = tid; i < XCH*M2*ISZ; i += 512){
          const int r = i / (XCH*ISZ), rem = i % (XCH*ISZ);
          const int ts = rem / ISZ, k = rem % ISZ;
          s_x[(ts*M2 + r)*8 + k] =
            f2bf(x[(size_t)(row0 + r)*(SEQ*ISZ) + (size_t)(t + ts)*ISZ + k]);
        }
        __syncthreads();
      }
      if (t >= SEQ) waitge(curf, t - SEQ + 1, abt);

      const int pb = t & 1, qb = pb ^ 1;
      short* h0q = &s_h0[qb][0];
      short* h0p = &s_h0[pb][0];

      #pragma unroll
      for (int rt = 0; rt < 2; rt++){
        bf16x8 ax;
        if (t < SEQ){
          ax = *(const bf16x8*)((lq == 0) ?
              (s_x + (((t & (XCH-1)))*M2 + rt*16 + l15)*8) : s_zp);
        } else {
          if (lq == 0){
            const char* cp = curring + ((t - SEQ) % NS)*512 + (rt*16 + l15)*16;
            union { unsigned long long q[2]; bf16x8 v; } uu;
            uu.q[0] = ald64(cp); uu.q[1] = ald64(cp + 8);
            ax = uu.v;
          } else ax = *(const bf16x8*)s_zp;
        }
        f32x4 acc[4];
        #pragma unroll
        for (int g = 0; g < 4; g++){
          const bf16x8 bw = *(const bf16x8*)((lq == 0) ? (s_wih0 + (g*128 + u)*8) : s_zp);
          f32x4 ci; ci[0]=bias0[g]; ci[1]=bias0[g]; ci[2]=bias0[g]; ci[3]=bias0[g];
          acc[g] = __builtin_amdgcn_mfma_f32_16x16x32_bf16(ax, bw, ci, 0, 0, 0);
        }
        #pragma unroll
        for (int kt = 0; kt < 4; kt++){
          const bf16x8 a = *(const bf16x8*)(h0q + (rt*16 + l15)*HP + (kt*4 + lq)*8);
          #pragma unroll
          for (int g = 0; g < 4; g++)
            acc[g] = __builtin_amdgcn_mfma_f32_16x16x32_bf16(a, whh0f[g][kt], acc[g], 0, 0, 0);
        }
        #pragma unroll
        for (int j = 0; j < 4; j++){
          const float iv = sigf(acc[0][j]);
          const float fv = sigf(acc[1][j]);
          const float gv = tanhf_(acc[2][j]);
          const float ov = sigf(acc[3][j]);
          c0[rt][j] = fv*c0[rt][j] + iv*gv;
          const float h = ov * tanhf_(c0[rt][j]);
          h0p[(rt*16 + lq*4 + j)*HP + u] = f2bf(h);
        }
      }
      __syncthreads();                         // h0(t) complete in LDS
      {
        const int r = tid >> 4, seg = tid & 15;
        const short* sp = h0p + r*HP + seg*8;
        char* dp = h0ring + (t % NS)*8192 + tid*16;
        ast64(dp,     *(const unsigned long long*)(sp));
        ast64(dp + 8, *(const unsigned long long*)(sp + 4));
      }
      __syncthreads();                         // drains ring stores (vmcnt)
      if (tid == 0) astf(h0f, t + 1);
    }
  } else {
    // ================= L1: layer 1 + fc; streams wih1 only =================
    __shared__ __align__(16) short s_land[M2*HP];    // 8704B
    __shared__ __align__(16) short s_h1[2][M2*HP];   // 17408B
    __shared__ __align__(16) float s_fcw[ISZ*HSZ];   // 3072B
    __shared__ __align__(16) short s_ct[M2*8];       // 512B
    __shared__ float s_fcb[8];
    __shared__ __align__(16) short s_zp[8];

    // wih1 -> ws pack (redundant identical writes across L1 blocks; each
    // thread reads back slots it wrote itself -> fb-proven self-coherent)
    #pragma unroll
    for (int g = 0; g < 4; g++){
      const int c = g*128 + u;
      #pragma unroll
      for (int kt = 0; kt < 4; kt++){
        const float* wp = w_ih1 + c*HSZ + kt*32 + lq*8;
        bf16x8 f;
        #pragma unroll
        for (int i = 0; i < 8; i++) f[i] = f2bf(wp[i]);
        *(bf16x8*)(w1p + (((wv*4 + g)*4 + kt)*64 + lane)*8) = f;
      }
    }
    bf16x8 whh1f[4][4];
    float bias1[4];
    #pragma unroll
    for (int g = 0; g < 4; g++){
      const int c = g*128 + u;
      bias1[g] = b_ih1[c] + b_hh1[c];
      #pragma unroll
      for (int kt = 0; kt < 4; kt++){
        const float* wp = w_hh1 + c*HSZ + kt*32 + lq*8;
        bf16x8 f;
        #pragma unroll
        for (int i = 0; i < 8; i++) f[i] = f2bf(wp[i]);
        whh1f[g][kt] = f;
      }
    }
    for (int i = tid; i < 2*M2*HP; i += 512) (&s_h1[0][0])[i] = 0;
    for (int i = tid; i < ISZ*HSZ; i += 512) s_fcw[i] = fc_w[i];
    if (tid < 8){ s_fcb[tid] = (tid < 6) ? fc_b[tid] : 0.f; s_zp[tid] = 0; }
    if (tid < M2*8) s_ct[tid] = 0;
    float c1[2][4] = {{0.f,0.f,0.f,0.f},{0.f,0.f,0.f,0.f}};
    __syncthreads();

    for (int t = 0; t < TSTEPS; ++t){
      #pragma unroll
      for (int g = 0; g < 4; g++){
        #pragma unroll
        for (int kt = 0; kt < 4; kt++) PIN(whh1f[g][kt]);
      }
      waitge(h0f, t + 1, abt);
      {  // land h0(t): ring -> LDS
        const int r = tid >> 4, seg = tid & 15;
        const char* sp = h0ring + (t % NS)*8192 + tid*16;
        short* dp = s_land + r*HP + seg*8;
        *(unsigned long long*)(dp)     = ald64(sp);
        *(unsigned long long*)(dp + 4) = ald64(sp + 8);
      }
      __syncthreads();                         // land ready
      if (tid == 0) astf(consf, t + 1);        // slot consumed

      const int pb = t & 1, qb = pb ^ 1;
      short* h1q = &s_h1[qb][0];
      short* h1p = &s_h1[pb][0];

      #pragma unroll
      for (int rt = 0; rt < 2; rt++){
        f32x4 acc[4];
        #pragma unroll
        for (int g = 0; g < 4; g++){
          acc[g][0]=bias1[g]; acc[g][1]=bias1[g]; acc[g][2]=bias1[g]; acc[g][3]=bias1[g];
        }
        #pragma unroll
        for (int kt = 0; kt < 4; kt++){        // h0(t) @ wih1^T (streamed B)
          const bf16x8 a = *(const bf16x8*)(s_land + (rt*16 + l15)*HP + (kt*4 + lq)*8);
          #pragma unroll
          for (int g = 0; g < 4; g++){
            const bf16x8 b = *(const bf16x8*)(w1p + (((wv*4 + g)*4 + kt)*64 + lane)*8);
            acc[g] = __builtin_amdgcn_mfma_f32_16x16x32_bf16(a, b, acc[g], 0, 0, 0);
          }
        }
        #pragma unroll
        for (int kt = 0; kt < 4; kt++){        // h1(t-1) @ whh1^T (reg B)
          const bf16x8 a = *(const bf16x8*)(h1q + (rt*16 + l15)*HP + (kt*4 + lq)*8);
          #pragma unroll
          for (int g = 0; g < 4; g++)
            acc[g] = __builtin_amdgcn_mfma_f32_16x16x32_bf16(a, whh1f[g][kt], acc[g], 0, 0, 0);
        }
        #pragma unroll
        for (int j = 0; j < 4; j++){
          const float iv = sigf(acc[0][j]);
          const float fv = sigf(acc[1][j]);
          const float gv = tanhf_(acc[2][j]);
          const float ov = sigf(acc[3][j]);
          c1[rt][j] = fv*c1[rt][j] + iv*gv;
          const float h = ov * tanhf_(c1[rt][j]);
          h1p[(rt*16 + lq*4 + j)*HP + u] = f2bf(h);
        }
      }
      __syncthreads();                         // h1(t) complete
      if (t >= SEQ - 1){
        if (tid < M2*ISZ){                     // 192 threads: fc head
          const int r = tid / 6, ii = tid % 6;
          float sacc = 0.f;
          #pragma unroll 4
          for (int kk = 0; kk < 128; kk++)
            sacc += bf2f((unsigned short)h1p[r*HP + kk]) * s_fcw[ii*128 + kk];
          const float pred = tanhf_(s_fcb[ii] + sacc);
          s_ct[r*8 + ii] = f2bf(pred);
          if (t >= SEQ)
            out[(size_t)(row0 + r)*(PRED*ISZ) + (size_t)(t - SEQ)*ISZ + ii] = pred;
        }
        __syncthreads();                       // s_ct ready
        if (tid < 32){
          char* dp = curring + ((t - (SEQ-1)) % NS)*512 + tid*16;
          ast64(dp,     *(const unsigned long long*)(s_ct + tid*8));
          ast64(dp + 8, *(const unsigned long long*)(s_ct + tid*8 + 4));
        }
        __syncthreads();                       // drains cur stores
        if (tid == 0) astf(curf, t - SEQ + 2);
      }
    }
  }
}

// ================= fallback: round-11 kernel (proven, 3.2ms) ===============
template<int PRECVT>
__global__
__attribute__((amdgpu_flat_work_group_size(512, 512)))
void lstm_fb(
    const float* __restrict__ x,
    const float* __restrict__ w_ih0, const float* __restrict__ w_hh0,
    const float* __restrict__ b_ih0, const float* __restrict__ b_hh0,
    const float* __restrict__ w_ih1, const float* __restrict__ w_hh1,
    const float* __restrict__ b_ih1, const float* __restrict__ b_hh1,
    const float* __restrict__ fc_w, const float* __restrict__ fc_b,
    float* __restrict__ out, unsigned short* __restrict__ wsb)
{
  __shared__ short s_whh1[65536];
  __shared__ short s_h0[2][16*HP];
  __shared__ short s_h1[16*HP];
  __shared__ short s_x[(XCH+1)*16*8];
  __shared__ short s_wih0[512*8];
  __shared__ float s_bias[2*512];
  __shared__ float s_fcb[8];
  __shared__ short s_zpad[8];

  const int tid  = threadIdx.x;
  const int wv   = tid >> 6;
  const int lane = tid & 63;
  const int l15  = lane & 15;
  const int lq   = lane >> 4;
  const int u    = wv*16 + l15;
  const int row0 = blockIdx.x * 16;
  char* const whh1b = (char*)s_whh1;

  for (int i = tid; i < 2*16*HP; i += 512) (&s_h0[0][0])[i] = 0;
  for (int i = tid; i < 16*HP;   i += 512) s_h1[i] = 0;
  for (int i = tid; i < (XCH+1)*16*8; i += 512) s_x[i] = 0;
  if (tid < 8){ s_zpad[tid] = 0; s_fcb[tid] = (tid < 6) ? fc_b[tid] : 0.f; }
  {
    #pragma unroll
    for (int k = 0; k < 6; k++) s_wih0[tid*8 + k] = f2bf(w_ih0[tid*6 + k]);
    s_wih0[tid*8 + 6] = 0; s_wih0[tid*8 + 7] = 0;
  }
  for (int i = tid; i < 1024; i += 512)
    s_bias[i] = (i < 512) ? (b_ih0[i] + b_hh0[i]) : (b_ih1[i-512] + b_hh1[i-512]);
  for (int i = tid; i < 32768; i += 512){
    const int c = i >> 6, kp = i & 63;
    const unsigned lo = (unsigned short)f2bf(w_hh1[c*128 + 2*kp]);
    const unsigned hi = (unsigned short)f2bf(w_hh1[c*128 + 2*kp + 1]);
    *(unsigned*)(whh1b + ((i*4) ^ ((c & 7) << 4))) = lo | (hi << 16);
  }
  if (PRECVT){
    #pragma unroll
    for (int g = 0; g < 4; g++){
      const int c = g*128 + u;
      #pragma unroll
      for (int kt = 0; kt < 4; kt++){
        const float* wp = w_hh0 + c*HSZ + kt*32 + lq*8;
        bf16x8 f;
        #pragma unroll
        for (int i = 0; i < 8; i++) f[i] = f2bf(wp[i]);
        *(bf16x8*)(wsb + (((wv*4 + g)*4 + kt)*64 + lane)*8) = f;
      }
    }
  }
  bf16x8 wih1f[4][4];
  #pragma unroll
  for (int g = 0; g < 4; g++){
    const int c = g*128 + u;
    #pragma unroll
    for (int kt = 0; kt < 4; kt++){
      const float* wp = w_ih1 + c*HSZ + kt*32 + lq*8;
      bf16x8 f;
      #pragma unroll
      for (int i = 0; i < 8; i++) f[i] = f2bf(wp[i]);
      wih1f[g][kt] = f;
    }
  }
  float c0[4] = {0.f,0.f,0.f,0.f}, c1[4] = {0.f,0.f,0.f,0.f};
  volatile const float* vb = s_bias;
  __syncthreads();

  for (int t = 0; t < TSTEPS; ++t){
    #pragma unroll
    for (int g = 0; g < 4; g++){
      #pragma unroll
      for (int kt = 0; kt < 4; kt++) PIN(wih1f[g][kt]);
    }
    if (t < SEQ && (t & (XCH-1)) == 0){
      for (int i = tid; i < XCH*16*ISZ; i += 512){
        const int r = i / (XCH*ISZ), rem = i % (XCH*ISZ);
        const int ts = rem / ISZ, k = rem % ISZ;
        s_x[(ts*16 + r)*8 + k] =
          f2bf(x[(size_t)(row0 + r)*(SEQ*ISZ) + (size_t)(t + ts)*ISZ + k]);
      }
      __syncthreads();
    }
    const int tt = (t < SEQ) ? (t & (XCH-1)) : XCH;
    const int pb = t & 1, qb = pb ^ 1;

    const bf16x8 ax = *(const bf16x8*)((lq == 0) ? (s_x + (tt*16 + l15)*8) : s_zpad);
    f32x4 acc[4];
    #pragma unroll
    for (int g = 0; g < 4; g++){
      const bf16x8 bw = *(const bf16x8*)((lq == 0) ? (s_wih0 + (g*128 + u)*8) : s_zpad);
      const float bg = vb[g*128 + u];
      f32x4 ci; ci[0] = bg; ci[1] = bg; ci[2] = bg; ci[3] = bg;
      acc[g] = __builtin_amdgcn_mfma_f32_16x16x32_bf16(ax, bw, ci, 0, 0, 0);
    }
    #pragma unroll
    for (int kt = 0; kt < 4; kt++){
      bf16x8 stg[4];
      if (PRECVT){
        #pragma unroll
        for (int g = 0; g < 4; g++)
          stg[g] = *(const bf16x8*)(wsb + (((wv*4 + g)*4 + kt)*64 + lane)*8);
      } else {
        #pragma unroll
        for (int g = 0; g < 4; g++){
          const float* wp = w_hh0 + (g*128 + u)*HSZ + kt*32 + lq*8;
          bf16x8 f;
          #pragma unroll
          for (int i = 0; i < 8; i++) f[i] = f2bf(wp[i]);
          stg[g] = f;
        }
      }
      const bf16x8 a = *(const bf16x8*)(s_h0[qb] + l15*HP + (kt*4 + lq)*8);
      #pragma unroll
      for (int g = 0; g < 4; g++)
        acc[g] = __builtin_amdgcn_mfma_f32_16x16x32_bf16(a, stg[g], acc[g], 0, 0, 0);
    }
    #pragma unroll
    for (int j = 0; j < 4; j++){
      const float iv = sigf(acc[0][j]);
      const float fv = sigf(acc[1][j]);
      const float gv = tanhf_(acc[2][j]);
      const float ov = sigf(acc[3][j]);
      c0[j] = fv*c0[j] + iv*gv;
      const float h = ov * tanhf_(c0[j]);
      s_h0[pb][(lq*4 + j)*HP + u] = f2bf(h);
    }
    __syncthreads();

    #pragma unroll
    for (int g = 0; g < 4; g++){
      const float bg = vb[512 + g*128 + u];
      acc[g][0] = bg; acc[g][1] = bg; acc[g][2] = bg; acc[g][3] = bg;
    }
    #pragma unroll
    for (int kt = 0; kt < 4; kt++){
      const bf16x8 a = *(const bf16x8*)(s_h0[pb] + l15*HP + (kt*4 + lq)*8);
      #pragma unroll
      for (int g = 0; g < 4; g++)
        acc[g] = __builtin_amdgcn_mfma_f32_16x16x32_bf16(a, wih1f[g][kt], acc[g], 0, 0, 0);
    }
    #pragma unroll
    for (int kt = 0; kt < 4; kt++){
      const bf16x8 a = *(const bf16x8*)(s_h1 + l15*HP + (kt*4 + lq)*8);
      #pragma unroll
      for (int g = 0; g < 4; g++){
        const int c = g*128 + u;
        const bf16x8 b = *(const bf16x8*)(whh1b +
            ((c*256 + (kt*4 + lq)*16) ^ ((u & 7) << 4)));
        acc[g] = __builtin_amdgcn_mfma_f32_16x16x32_bf16(a, b, acc[g], 0, 0, 0);
      }
    }
    __syncthreads();
    const bool dofc = (t >= SEQ - 1);
    #pragma unroll
    for (int j = 0; j < 4; j++){
      const float iv = sigf(acc[0][j]);
      const float fv = sigf(acc[1][j]);
      const float gv = tanhf_(acc[2][j]);
      const float ov = sigf(acc[3][j]);
      c1[j] = fv*c1[j] + iv*gv;
      const float h = ov * tanhf_(c1[j]);
      s_h1[(lq*4 + j)*HP + u] = f2bf(h);
    }
    if (dofc){
      __syncthreads();
      if (tid < 96){
        const int r = tid / 6, ii = tid % 6;
        float sacc = 0.f;
        #pragma unroll 4
        for (int kk = 0; kk < 128; kk++)
          sacc += bf2f((unsigned short)s_h1[r*HP + kk]) * fc_w[ii*128 + kk];
        const float pred = tanhf_(s_fcb[ii] + sacc);
        s_x[(XCH*16 + r)*8 + ii] = f2bf(pred);
        if (t >= SEQ)
          out[(size_t)(row0 + r)*(PRED*ISZ) + (size_t)(t - SEQ)*ISZ + ii] = pred;
      }
      __syncthreads();
    }
  }
}

extern "C" void kernel_launch(void* const* d_in, const int* in_sizes, int n_in,
                              void* d_out, int out_size, void* d_ws, size_t ws_size,
                              hipStream_t stream) {
  const float* x     = (const float*)d_in[0];
  const float* w_ih0 = (const float*)d_in[1];
  const float* w_hh0 = (const float*)d_in[2];
  const float* b_ih0 = (const float*)d_in[3];
  const float* b_hh0 = (const float*)d_in[4];
  const float* w_ih1 = (const float*)d_in[5];
  const float* w_hh1 = (const float*)d_in[6];
  const float* b_ih1 = (const float*)d_in[7];
  const float* b_hh1 = (const float*)d_in[8];
  const float* fc_w  = (const float*)d_in[9];
  const float* fc_b  = (const float*)d_in[10];
  float* out = (float*)d_out;

  if (ws_size >= WS_NEED){
    hipMemsetAsync(d_ws, 0, FLAGBYTES, stream);
    lstm_pipe<<<dim3(2*NP), dim3(512), 0, stream>>>(
        x, w_ih0, w_hh0, b_ih0, b_hh0, w_ih1, w_hh1, b_ih1, b_hh1,
        fc_w, fc_b, out, (char*)d_ws);
  } else if (ws_size >= (size_t)131072){
    lstm_fb<1><<<dim3(256), dim3(512), 0, stream>>>(
        x, w_ih0, w_hh0, b_ih0, b_hh0, w_ih1, w_hh1, b_ih1, b_hh1,
        fc_w, fc_b, out, (unsigned short*)d_ws);
  } else {
    lstm_fb<0><<<dim3(256), dim3(512), 0, stream>>>(
        x, w_ih0, w_hh0, b_ih0, b_hh0, w_ih1, w_hh1, b_ih1, b_hh1,
        fc_w, fc_b, out, (unsigned short*)d_ws);
  }
}

// Round 15
// 8235.449 us; speedup vs baseline: 2.2421x; 2.2421x over previous
//
#include <hip/hip_runtime.h>

#define SEQ 1024
#define ISZ 6
#define HSZ 128
#define PRED 50
#define M2   32
#define NP   128
#define HP   136
#define XCH  8
#define NS   2
#define TSTEPS (SEQ + PRED)

// ---- d_ws layout (r12 proved ws_size >= 4.45MB) ----
#define F_H0   ((size_t)0)
#define F_CONS ((size_t)16384)
#define F_ABT  ((size_t)32768)
#define FLAGBYTES ((size_t)36992)
#define R_H0   ((size_t)36864)
#define R_C0   (R_H0 + (size_t)NP*NS*8192)
#define R_WHH0 (R_C0 + (size_t)NP*16384)
#define R_WIH0 (R_WHH0 + (size_t)131072)
#define WS_NEED (R_WIH0 + (size_t)32768)          // 4,395,008

// ---- LDS pool (one block/CU everywhere) ----
#define POOLB 160832
#define OW1P 0          // L1: whh1 pack (131072)
#define OH0D 131072     // L1: h0 land dbuf 2*32*HP*2 (17408)
#define OH1  148480     // L1: h1 single (8704)
#define OFCW 157184     // L1: fc_w f32 (3072)
#define OAR  160256     // L1: AR cur (512)
#define OFCB 160768     // L1: fc_b (32)
#define OZP1 160800     // L1: zeros (16)
#define LH0  0          // L0: h0 dbuf (17408)
#define LX   17408      // L0: x chunk (4096)
#define LW0  21504      // L0: wih0 (8192)
#define LZP0 29696      // L0: zeros (16)

using f32x4  = __attribute__((ext_vector_type(4))) float;
using bf16x8 = __attribute__((ext_vector_type(8))) short;

__device__ __forceinline__ short f2bf(float f){
  union { float f; unsigned u; } v; v.f = f;
  unsigned r = v.u + 0x7FFFu + ((v.u >> 16) & 1u);
  return (short)(r >> 16);
}
__device__ __forceinline__ float bf2f(unsigned short us){
  union { unsigned u; float f; } v; v.u = ((unsigned)us) << 16; return v.f;
}
__device__ __forceinline__ float sigf(float x){
  float e = __builtin_amdgcn_exp2f(x * -1.4426950408889634f);
  return __builtin_amdgcn_rcpf(1.0f + e);
}
__device__ __forceinline__ float tanhf_(float x){
  float e = __builtin_amdgcn_exp2f(x * 2.8853900817779268f);
  return 1.0f - 2.0f * __builtin_amdgcn_rcpf(1.0f + e);
}
#define PIN(v) asm volatile("" : "+v"(v))

__device__ __forceinline__ int aldf(const int* p){
  return __hip_atomic_load(p, __ATOMIC_ACQUIRE, __HIP_MEMORY_SCOPE_AGENT);
}
__device__ __forceinline__ void astf(int* p, int v){
  __hip_atomic_store(p, v, __ATOMIC_RELEASE, __HIP_MEMORY_SCOPE_AGENT);
}
// cached-flag wait: skips the (HBM-latency) atomic when a previous acquire
// already observed >= v. Sound: NS bounds the producer's lead, so any ring
// slot REUSE forces flag v' > last -> a real re-acquire (with cache inv)
// happens before stale data could be read. Sticky abort: deadlock -> ~0.3s
// garbage-finish instead of a 600s harness timeout.
__device__ __forceinline__ void waitge_c(const int* f, int v, int& last, int* abt){
  if (threadIdx.x == 0 && last < v){
    int n = 0, s = last;
    while ((s = aldf(f)) < v){
      if ((n & 63) == 0 &&
          __hip_atomic_load(abt, __ATOMIC_RELAXED, __HIP_MEMORY_SCOPE_AGENT)) break;
      __builtin_amdgcn_s_sleep(8);
      if (++n > (1 << 20)){ astf(abt, 1); break; }
    }
    last = (s > v) ? s : v;
  }
  __syncthreads();
}

// 256 blocks (r14-proven all-resident geometry): 128 L0 + 128 L1, M=32/pair.
// r14's 17.7us/step was agent-ATOMIC ring DATA (uncached, per-element HBM).
// v2: ring data = plain b128 ld/st through L2; atomics only for flags.
// SS phase is one-directional (L0 -> L1). L0 exits at t=SEQ (dumps c0 state);
// L1 runs the AR phase solo, streaming whh0/wih0 from self-written ws packs.
__global__
__attribute__((amdgpu_flat_work_group_size(512, 512)))
void lstm_pipe2(
    const float* __restrict__ x,
    const float* __restrict__ w_ih0, const float* __restrict__ w_hh0,
    const float* __restrict__ b_ih0, const float* __restrict__ b_hh0,
    const float* __restrict__ w_ih1, const float* __restrict__ w_hh1,
    const float* __restrict__ b_ih1, const float* __restrict__ b_hh1,
    const float* __restrict__ fc_w, const float* __restrict__ fc_b,
    float* __restrict__ out, char* __restrict__ ws)
{
  __shared__ __align__(16) char pool[POOLB];

  const int tid  = threadIdx.x;
  const int wv   = tid >> 6;
  const int lane = tid & 63;
  const int l15  = lane & 15;
  const int lq   = lane >> 4;
  const int u    = wv*16 + l15;
  const int type = (blockIdx.x >= NP) ? 1 : 0;
  const int p    = blockIdx.x & (NP-1);
  const int row0 = p * M2;

  int* h0f     = (int*)(ws + F_H0   + (size_t)p*128);
  int* consf   = (int*)(ws + F_CONS + (size_t)p*128);
  int* abt     = (int*)(ws + F_ABT);
  char* ring   = ws + R_H0 + (size_t)p*(NS*8192);
  float* c0s   = (float*)(ws + R_C0 + (size_t)p*16384);
  short* w0p   = (short*)(ws + R_WHH0);
  short* wi0p  = (short*)(ws + R_WIH0);
  int lastf = 0;

  if (type == 0){
    // ====================== L0: layer 0, SS only ======================
    short* s_h0   = (short*)(pool + LH0);
    short* s_x    = (short*)(pool + LX);
    short* s_wih0 = (short*)(pool + LW0);
    short* s_zp   = (short*)(pool + LZP0);

    for (int i = tid; i < 2*M2*HP; i += 512) s_h0[i] = 0;
    for (int i = tid; i < XCH*M2*8; i += 512) s_x[i] = 0;
    if (tid < 8) s_zp[tid] = 0;
    {
      #pragma unroll
      for (int k = 0; k < 6; k++) s_wih0[tid*8 + k] = f2bf(w_ih0[tid*6 + k]);
      s_wih0[tid*8 + 6] = 0; s_wih0[tid*8 + 7] = 0;
    }
    bf16x8 whh0f[4][4];
    float bias0[4];
    #pragma unroll
    for (int g = 0; g < 4; g++){
      const int c = g*128 + u;
      bias0[g] = b_ih0[c] + b_hh0[c];
      #pragma unroll
      for (int kt = 0; kt < 4; kt++){
        const float* wp = w_hh0 + c*HSZ + kt*32 + lq*8;
        bf16x8 f;
        #pragma unroll
        for (int i = 0; i < 8; i++) f[i] = f2bf(wp[i]);
        whh0f[g][kt] = f;
      }
    }
    float c0[2][4] = {{0.f,0.f,0.f,0.f},{0.f,0.f,0.f,0.f}};
    __syncthreads();

    for (int t = 0; t < SEQ; ++t){
      #pragma unroll
      for (int g = 0; g < 4; g++){
        #pragma unroll
        for (int kt = 0; kt < 4; kt++) PIN(whh0f[g][kt]);
      }
      if (t >= NS) waitge_c(consf, t - NS + 1, lastf, abt);

      if ((t & (XCH-1)) == 0){
        for (int i = tid; i < XCH*M2*ISZ; i += 512){
          const int r = i / (XCH*ISZ), rem = i % (XCH*ISZ);
          const int ts = rem / ISZ, k = rem % ISZ;
          s_x[(ts*M2 + r)*8 + k] =
            f2bf(x[(size_t)(row0 + r)*(SEQ*ISZ) + (size_t)(t + ts)*ISZ + k]);
        }
        __syncthreads();
      }
      const int pb = t & 1, qb = pb ^ 1;
      short* h0q = s_h0 + qb*(M2*HP);
      short* h0p = s_h0 + pb*(M2*HP);

      #pragma unroll
      for (int rt = 0; rt < 2; rt++){
        const bf16x8 ax = *(const bf16x8*)((lq == 0) ?
            (s_x + ((t & (XCH-1))*M2 + rt*16 + l15)*8) : s_zp);
        f32x4 acc[4];
        #pragma unroll
        for (int g = 0; g < 4; g++){
          const bf16x8 bw = *(const bf16x8*)((lq == 0) ? (s_wih0 + (g*128 + u)*8) : s_zp);
          f32x4 ci; ci[0]=bias0[g]; ci[1]=bias0[g]; ci[2]=bias0[g]; ci[3]=bias0[g];
          acc[g] = __builtin_amdgcn_mfma_f32_16x16x32_bf16(ax, bw, ci, 0, 0, 0);
        }
        #pragma unroll
        for (int kt = 0; kt < 4; kt++){
          const bf16x8 a = *(const bf16x8*)(h0q + (rt*16 + l15)*HP + (kt*4 + lq)*8);
          #pragma unroll
          for (int g = 0; g < 4; g++)
            acc[g] = __builtin_amdgcn_mfma_f32_16x16x32_bf16(a, whh0f[g][kt], acc[g], 0, 0, 0);
        }
        #pragma unroll
        for (int j = 0; j < 4; j++){
          const float iv = sigf(acc[0][j]);
          const float fv = sigf(acc[1][j]);
          const float gv = tanhf_(acc[2][j]);
          const float ov = sigf(acc[3][j]);
          c0[rt][j] = fv*c0[rt][j] + iv*gv;
          const float h = ov * tanhf_(c0[rt][j]);
          h0p[(rt*16 + lq*4 + j)*HP + u] = f2bf(h);
        }
      }
      __syncthreads();                         // h0(t) complete in LDS
      {  // ring publish: PLAIN b128 stores (through L2, coalesced)
        const int r = tid >> 4, seg = tid & 15;
        *(uint4*)(ring + (t % NS)*8192 + tid*16) =
            *(const uint4*)(h0p + r*HP + seg*8);
      }
      if (t == SEQ-1){                         // c0 state handoff
        #pragma unroll
        for (int rt = 0; rt < 2; rt++)
          #pragma unroll
          for (int j = 0; j < 4; j++)
            c0s[(rt*16 + lq*4 + j)*128 + u] = c0[rt][j];
      }
      __syncthreads();                         // drains all stores (vmcnt)
      if (tid == 0) astf(h0f, t + 1);          // release publishes them
    }
  } else {
    // ====================== L1: layer 1 + solo AR ======================
    char*  w1l   = pool + OW1P;                // whh1 swizzled pack
    short* s_h0d = (short*)(pool + OH0D);      // landed h0 dbuf
    short* s_h1  = (short*)(pool + OH1);
    float* s_fcw = (float*)(pool + OFCW);
    short* s_ar  = (short*)(pool + OAR);
    float* s_fcb = (float*)(pool + OFCB);
    short* s_zp  = (short*)(pool + OZP1);

    // whh1 -> LDS pack, XOR-swizzled (r11-proven write+read pair)
    for (int i = tid; i < 32768; i += 512){
      const int c = i >> 6, kp = i & 63;
      const unsigned lo = (unsigned short)f2bf(w_hh1[c*128 + 2*kp]);
      const unsigned hi = (unsigned short)f2bf(w_hh1[c*128 + 2*kp + 1]);
      *(unsigned*)(w1l + ((i*4) ^ ((c & 7) << 4))) = lo | (hi << 16);
    }
    // AR packs -> ws (each thread later reads only slots it wrote itself)
    #pragma unroll
    for (int g = 0; g < 4; g++){
      const int c = g*128 + u;
      #pragma unroll
      for (int kt = 0; kt < 4; kt++){
        const float* wp = w_hh0 + c*HSZ + kt*32 + lq*8;
        bf16x8 f;
        #pragma unroll
        for (int i = 0; i < 8; i++) f[i] = f2bf(wp[i]);
        *(bf16x8*)(w0p + (((wv*4 + g)*4 + kt)*64 + lane)*8) = f;
      }
      bf16x8 fi;
      #pragma unroll
      for (int i = 0; i < 8; i++)
        fi[i] = (lq == 0 && i < 6) ? f2bf(w_ih0[c*6 + i]) : (short)0;
      *(bf16x8*)(wi0p + ((wv*4 + g)*64 + lane)*8) = fi;
    }
    bf16x8 wih1f[4][4];
    float bias1[4], bias0[4];
    #pragma unroll
    for (int g = 0; g < 4; g++){
      const int c = g*128 + u;
      bias1[g] = b_ih1[c] + b_hh1[c];
      bias0[g] = b_ih0[c] + b_hh0[c];
      #pragma unroll
      for (int kt = 0; kt < 4; kt++){
        const float* wp = w_ih1 + c*HSZ + kt*32 + lq*8;
        bf16x8 f;
        #pragma unroll
        for (int i = 0; i < 8; i++) f[i] = f2bf(wp[i]);
        wih1f[g][kt] = f;
      }
    }
    for (int i = tid; i < 2*M2*HP; i += 512) s_h0d[i] = 0;
    for (int i = tid; i < M2*HP;   i += 512) s_h1[i] = 0;
    for (int i = tid; i < ISZ*HSZ; i += 512) s_fcw[i] = fc_w[i];
    if (tid < 8){ s_fcb[tid] = (tid < 6) ? fc_b[tid] : 0.f; s_zp[tid] = 0; }
    if (tid < M2*8) s_ar[tid] = 0;
    float c1[2][4] = {{0.f,0.f,0.f,0.f},{0.f,0.f,0.f,0.f}};
    __syncthreads();

    // -------- SS phase --------
    for (int t = 0; t < SEQ; ++t){
      #pragma unroll
      for (int g = 0; g < 4; g++){
        #pragma unroll
        for (int kt = 0; kt < 4; kt++) PIN(wih1f[g][kt]);
      }
      waitge_c(h0f, t + 1, lastf, abt);
      short* h0p = s_h0d + (t & 1)*(M2*HP);
      {  // land: PLAIN b128 loads (L2 path) -> LDS
        const int r = tid >> 4, seg = tid & 15;
        *(uint4*)(h0p + r*HP + seg*8) =
            *(const uint4*)(ring + (t % NS)*8192 + tid*16);
      }
      __syncthreads();                         // land visible
      if (tid == 0) astf(consf, t + 1);

      #pragma unroll
      for (int rt = 0; rt < 2; rt++){
        f32x4 acc[4];
        #pragma unroll
        for (int g = 0; g < 4; g++){
          acc[g][0]=bias1[g]; acc[g][1]=bias1[g]; acc[g][2]=bias1[g]; acc[g][3]=bias1[g];
        }
        #pragma unroll
        for (int kt = 0; kt < 4; kt++){        // h0(t) @ wih1^T (reg B)
          const bf16x8 a = *(const bf16x8*)(h0p + (rt*16 + l15)*HP + (kt*4 + lq)*8);
          #pragma unroll
          for (int g = 0; g < 4; g++)
            acc[g] = __builtin_amdgcn_mfma_f32_16x16x32_bf16(a, wih1f[g][kt], acc[g], 0, 0, 0);
        }
        #pragma unroll
        for (int kt = 0; kt < 4; kt++){        // h1(t-1) @ whh1^T (LDS B)
          const bf16x8 a = *(const bf16x8*)(s_h1 + (rt*16 + l15)*HP + (kt*4 + lq)*8);
          #pragma unroll
          for (int g = 0; g < 4; g++){
            const int c = g*128 + u;
            const bf16x8 b = *(const bf16x8*)(w1l +
                ((c*256 + (kt*4 + lq)*16) ^ ((u & 7) << 4)));
            acc[g] = __builtin_amdgcn_mfma_f32_16x16x32_bf16(a, b, acc[g], 0, 0, 0);
          }
        }
        __syncthreads();   // all reads of h1 rows [rt*16,rt*16+16) done
        #pragma unroll
        for (int j = 0; j < 4; j++){
          const float iv = sigf(acc[0][j]);
          const float fv = sigf(acc[1][j]);
          const float gv = tanhf_(acc[2][j]);
          const float ov = sigf(acc[3][j]);
          c1[rt][j] = fv*c1[rt][j] + iv*gv;
          const float h = ov * tanhf_(c1[rt][j]);
          s_h1[(rt*16 + lq*4 + j)*HP + u] = f2bf(h);
        }
      }
      if (t == SEQ-1){                         // seed AR input
        __syncthreads();
        if (tid < M2*ISZ){
          const int r = tid / 6, ii = tid % 6;
          float sacc = 0.f;
          #pragma unroll 4
          for (int kk = 0; kk < 128; kk++)
            sacc += bf2f((unsigned short)s_h1[r*HP + kk]) * s_fcw[ii*128 + kk];
          s_ar[r*8 + ii] = f2bf(tanhf_(s_fcb[ii] + sacc));
        }
        __syncthreads();
      }
    }

    // -------- AR phase (solo) --------
    float c0[2][4];
    #pragma unroll
    for (int rt = 0; rt < 2; rt++)
      #pragma unroll
      for (int j = 0; j < 4; j++)
        c0[rt][j] = c0s[(rt*16 + lq*4 + j)*128 + u];

    for (int t = SEQ; t < TSTEPS; ++t){
      #pragma unroll
      for (int g = 0; g < 4; g++){
        #pragma unroll
        for (int kt = 0; kt < 4; kt++) PIN(wih1f[g][kt]);
      }
      const int pb = t & 1, qb = pb ^ 1;
      short* h0q = s_h0d + qb*(M2*HP);
      short* h0p = s_h0d + pb*(M2*HP);

      // layer 0: cur @ wih0 + h0 @ whh0 (both streamed from ws packs)
      #pragma unroll
      for (int rt = 0; rt < 2; rt++){
        const bf16x8 ax = *(const bf16x8*)((lq == 0) ?
            (s_ar + (rt*16 + l15)*8) : s_zp);
        f32x4 acc[4];
        #pragma unroll
        for (int g = 0; g < 4; g++){
          const bf16x8 bw = *(const bf16x8*)(wi0p + ((wv*4 + g)*64 + lane)*8);
          f32x4 ci; ci[0]=bias0[g]; ci[1]=bias0[g]; ci[2]=bias0[g]; ci[3]=bias0[g];
          acc[g] = __builtin_amdgcn_mfma_f32_16x16x32_bf16(ax, bw, ci, 0, 0, 0);
        }
        #pragma unroll
        for (int kt = 0; kt < 4; kt++){
          const bf16x8 a = *(const bf16x8*)(h0q + (rt*16 + l15)*HP + (kt*4 + lq)*8);
          #pragma unroll
          for (int g = 0; g < 4; g++){
            const bf16x8 b = *(const bf16x8*)(w0p + (((wv*4 + g)*4 + kt)*64 + lane)*8);
            acc[g] = __builtin_amdgcn_mfma_f32_16x16x32_bf16(a, b, acc[g], 0, 0, 0);
          }
        }
        #pragma unroll
        for (int j = 0; j < 4; j++){
          const float iv = sigf(acc[0][j]);
          const float fv = sigf(acc[1][j]);
          const float gv = tanhf_(acc[2][j]);
          const float ov = sigf(acc[3][j]);
          c0[rt][j] = fv*c0[rt][j] + iv*gv;
          const float h = ov * tanhf_(c0[rt][j]);
          h0p[(rt*16 + lq*4 + j)*HP + u] = f2bf(h);
        }
      }
      __syncthreads();                         // h0(t) complete

      // layer 1 (same as SS)
      #pragma unroll
      for (int rt = 0; rt < 2; rt++){
        f32x4 acc[4];
        #pragma unroll
        for (int g = 0; g < 4; g++){
          acc[g][0]=bias1[g]; acc[g][1]=bias1[g]; acc[g][2]=bias1[g]; acc[g][3]=bias1[g];
        }
        #pragma unroll
        for (int kt = 0; kt < 4; kt++){
          const bf16x8 a = *(const bf16x8*)(h0p + (rt*16 + l15)*HP + (kt*4 + lq)*8);
          #pragma unroll
          for (int g = 0; g < 4; g++)
            acc[g] = __builtin_amdgcn_mfma_f32_16x16x32_bf16(a, wih1f[g][kt], acc[g], 0, 0, 0);
        }
        #pragma unroll
        for (int kt = 0; kt < 4; kt++){
          const bf16x8 a = *(const bf16x8*)(s_h1 + (rt*16 + l15)*HP + (kt*4 + lq)*8);
          #pragma unroll
          for (int g = 0; g < 4; g++){
            const int c = g*128 + u;
            const bf16x8 b = *(const bf16x8*)(w1l +
                ((c*256 + (kt*4 + lq)*16) ^ ((u & 7) << 4)));
            acc[g] = __builtin_amdgcn_mfma_f32_16x16x32_bf16(a, b, acc[g], 0, 0, 0);
          }
        }
        __syncthreads();
        #pragma unroll
        for (int j = 0; j < 4; j++){
          const float iv = sigf(acc[0][j]);
          const float fv = sigf(acc[1][j]);
          const float gv = tanhf_(acc[2][j]);
          const float ov = sigf(acc[3][j]);
          c1[rt][j] = fv*c1[rt][j] + iv*gv;
          const float h = ov * tanhf_(c1[rt][j]);
          s_h1[(rt*16 + lq*4 + j)*HP + u] = f2bf(h);
        }
      }
      __syncthreads();                         // h1(t) complete
      if (tid < M2*ISZ){
        const int r = tid / 6, ii = tid % 6;
        float sacc = 0.f;
        #pragma unroll 4
        for (int kk = 0; kk < 128; kk++)
          sacc += bf2f((unsigned short)s_h1[r*HP + kk]) * s_fcw[ii*128 + kk];
        const float pred = tanhf_(s_fcb[ii] + sacc);
        s_ar[r*8 + ii] = f2bf(pred);
        out[(size_t)(row0 + r)*(PRED*ISZ) + (size_t)(t - SEQ)*ISZ + ii] = pred;
      }
      __syncthreads();                         // cur ready for next step
    }
  }
}

// ================= fallback: round-11 kernel (proven, 3.2ms) ===============
template<int PRECVT>
__global__
__attribute__((amdgpu_flat_work_group_size(512, 512)))
void lstm_fb(
    const float* __restrict__ x,
    const float* __restrict__ w_ih0, const float* __restrict__ w_hh0,
    const float* __restrict__ b_ih0, const float* __restrict__ b_hh0,
    const float* __restrict__ w_ih1, const float* __restrict__ w_hh1,
    const float* __restrict__ b_ih1, const float* __restrict__ b_hh1,
    const float* __restrict__ fc_w, const float* __restrict__ fc_b,
    float* __restrict__ out, unsigned short* __restrict__ wsb)
{
  __shared__ short s_whh1[65536];
  __shared__ short s_h0[2][16*HP];
  __shared__ short s_h1[16*HP];
  __shared__ short s_x[(XCH+1)*16*8];
  __shared__ short s_wih0[512*8];
  __shared__ float s_bias[2*512];
  __shared__ float s_fcb[8];
  __shared__ short s_zpad[8];

  const int tid  = threadIdx.x;
  const int wv   = tid >> 6;
  const int lane = tid & 63;
  const int l15  = lane & 15;
  const int lq   = lane >> 4;
  const int u    = wv*16 + l15;
  const int row0 = blockIdx.x * 16;
  char* const whh1b = (char*)s_whh1;

  for (int i = tid; i < 2*16*HP; i += 512) (&s_h0[0][0])[i] = 0;
  for (int i = tid; i < 16*HP;   i += 512) s_h1[i] = 0;
  for (int i = tid; i < (XCH+1)*16*8; i += 512) s_x[i] = 0;
  if (tid < 8){ s_zpad[tid] = 0; s_fcb[tid] = (tid < 6) ? fc_b[tid] : 0.f; }
  {
    #pragma unroll
    for (int k = 0; k < 6; k++) s_wih0[tid*8 + k] = f2bf(w_ih0[tid*6 + k]);
    s_wih0[tid*8 + 6] = 0; s_wih0[tid*8 + 7] = 0;
  }
  for (int i = tid; i < 1024; i += 512)
    s_bias[i] = (i < 512) ? (b_ih0[i] + b_hh0[i]) : (b_ih1[i-512] + b_hh1[i-512]);
  for (int i = tid; i < 32768; i += 512){
    const int c = i >> 6, kp = i & 63;
    const unsigned lo = (unsigned short)f2bf(w_hh1[c*128 + 2*kp]);
    const unsigned hi = (unsigned short)f2bf(w_hh1[c*128 + 2*kp + 1]);
    *(unsigned*)(whh1b + ((i*4) ^ ((c & 7) << 4))) = lo | (hi << 16);
  }
  if (PRECVT){
    #pragma unroll
    for (int g = 0; g < 4; g++){
      const int c = g*128 + u;
      #pragma unroll
      for (int kt = 0; kt < 4; kt++){
        const float* wp = w_hh0 + c*HSZ + kt*32 + lq*8;
        bf16x8 f;
        #pragma unroll
        for (int i = 0; i < 8; i++) f[i] = f2bf(wp[i]);
        *(bf16x8*)(wsb + (((wv*4 + g)*4 + kt)*64 + lane)*8) = f;
      }
    }
  }
  bf16x8 wih1f[4][4];
  #pragma unroll
  for (int g = 0; g < 4; g++){
    const int c = g*128 + u;
    #pragma unroll
    for (int kt = 0; kt < 4; kt++){
      const float* wp = w_ih1 + c*HSZ + kt*32 + lq*8;
      bf16x8 f;
      #pragma unroll
      for (int i = 0; i < 8; i++) f[i] = f2bf(wp[i]);
      wih1f[g][kt] = f;
    }
  }
  float c0[4] = {0.f,0.f,0.f,0.f}, c1[4] = {0.f,0.f,0.f,0.f};
  volatile const float* vb = s_bias;
  __syncthreads();

  for (int t = 0; t < TSTEPS; ++t){
    #pragma unroll
    for (int g = 0; g < 4; g++){
      #pragma unroll
      for (int kt = 0; kt < 4; kt++) PIN(wih1f[g][kt]);
    }
    if (t < SEQ && (t & (XCH-1)) == 0){
      for (int i = tid; i < XCH*16*ISZ; i += 512){
        const int r = i / (XCH*ISZ), rem = i % (XCH*ISZ);
        const int ts = rem / ISZ, k = rem % ISZ;
        s_x[(ts*16 + r)*8 + k] =
          f2bf(x[(size_t)(row0 + r)*(SEQ*ISZ) + (size_t)(t + ts)*ISZ + k]);
      }
      __syncthreads();
    }
    const int tt = (t < SEQ) ? (t & (XCH-1)) : XCH;
    const int pb = t & 1, qb = pb ^ 1;

    const bf16x8 ax = *(const bf16x8*)((lq == 0) ? (s_x + (tt*16 + l15)*8) : s_zpad);
    f32x4 acc[4];
    #pragma unroll
    for (int g = 0; g < 4; g++){
      const bf16x8 bw = *(const bf16x8*)((lq == 0) ? (s_wih0 + (g*128 + u)*8) : s_zpad);
      const float bg = vb[g*128 + u];
      f32x4 ci; ci[0] = bg; ci[1] = bg; ci[2] = bg; ci[3] = bg;
      acc[g] = __builtin_amdgcn_mfma_f32_16x16x32_bf16(ax, bw, ci, 0, 0, 0);
    }
    #pragma unroll
    for (int kt = 0; kt < 4; kt++){
      bf16x8 stg[4];
      if (PRECVT){
        #pragma unroll
        for (int g = 0; g < 4; g++)
          stg[g] = *(const bf16x8*)(wsb + (((wv*4 + g)*4 + kt)*64 + lane)*8);
      } else {
        #pragma unroll
        for (int g = 0; g < 4; g++){
          const float* wp = w_hh0 + (g*128 + u)*HSZ + kt*32 + lq*8;
          bf16x8 f;
          #pragma unroll
          for (int i = 0; i < 8; i++) f[i] = f2bf(wp[i]);
          stg[g] = f;
        }
      }
      const bf16x8 a = *(const bf16x8*)(s_h0[qb] + l15*HP + (kt*4 + lq)*8);
      #pragma unroll
      for (int g = 0; g < 4; g++)
        acc[g] = __builtin_amdgcn_mfma_f32_16x16x32_bf16(a, stg[g], acc[g], 0, 0, 0);
    }
    #pragma unroll
    for (int j = 0; j < 4; j++){
      const float iv = sigf(acc[0][j]);
      const float fv = sigf(acc[1][j]);
      const float gv = tanhf_(acc[2][j]);
      const float ov = sigf(acc[3][j]);
      c0[j] = fv*c0[j] + iv*gv;
      const float h = ov * tanhf_(c0[j]);
      s_h0[pb][(lq*4 + j)*HP + u] = f2bf(h);
    }
    __syncthreads();

    #pragma unroll
    for (int g = 0; g < 4; g++){
      const float bg = vb[512 + g*128 + u];
      acc[g][0] = bg; acc[g][1] = bg; acc[g][2] = bg; acc[g][3] = bg;
    }
    #pragma unroll
    for (int kt = 0; kt < 4; kt++){
      const bf16x8 a = *(const bf16x8*)(s_h0[pb] + l15*HP + (kt*4 + lq)*8);
      #pragma unroll
      for (int g = 0; g < 4; g++)
        acc[g] = __builtin_amdgcn_mfma_f32_16x16x32_bf16(a, wih1f[g][kt], acc[g], 0, 0, 0);
    }
    #pragma unroll
    for (int kt = 0; kt < 4; kt++){
      const bf16x8 a = *(const bf16x8*)(s_h1 + l15*HP + (kt*4 + lq)*8);
      #pragma unroll
      for (int g = 0; g < 4; g++){
        const int c = g*128 + u;
        const bf16x8 b = *(const bf16x8*)(whh1b +
            ((c*256 + (kt*4 + lq)*16) ^ ((u & 7) << 4)));
        acc[g] = __builtin_amdgcn_mfma_f32_16x16x32_bf16(a, b, acc[g], 0, 0, 0);
      }
    }
    __syncthreads();
    const bool dofc = (t >= SEQ - 1);
    #pragma unroll
    for (int j = 0; j < 4; j++){
      const float iv = sigf(acc[0][j]);
      const float fv = sigf(acc[1][j]);
      const float gv = tanhf_(acc[2][j]);
      const float ov = sigf(acc[3][j]);
      c1[j] = fv*c1[j] + iv*gv;
      const float h = ov * tanhf_(c1[j]);
      s_h1[(lq*4 + j)*HP + u] = f2bf(h);
    }
    if (dofc){
      __syncthreads();
      if (tid < 96){
        const int r = tid / 6, ii = tid % 6;
        float sacc = 0.f;
        #pragma unroll 4
        for (int kk = 0; kk < 128; kk++)
          sacc += bf2f((unsigned short)s_h1[r*HP + kk]) * fc_w[ii*128 + kk];
        const float pred = tanhf_(s_fcb[ii] + sacc);
        s_x[(XCH*16 + r)*8 + ii] = f2bf(pred);
        if (t >= SEQ)
          out[(size_t)(row0 + r)*(PRED*ISZ) + (size_t)(t - SEQ)*ISZ + ii] = pred;
      }
      __syncthreads();
    }
  }
}

extern "C" void kernel_launch(void* const* d_in, const int* in_sizes, int n_in,
                              void* d_out, int out_size, void* d_ws, size_t ws_size,
                              hipStream_t stream) {
  const float* x     = (const float*)d_in[0];
  const float* w_ih0 = (const float*)d_in[1];
  const float* w_hh0 = (const float*)d_in[2];
  const float* b_ih0 = (const float*)d_in[3];
  const float* b_hh0 = (const float*)d_in[4];
  const float* w_ih1 = (const float*)d_in[5];
  const float* w_hh1 = (const float*)d_in[6];
  const float* b_ih1 = (const float*)d_in[7];
  const float* b_hh1 = (const float*)d_in[8];
  const float* fc_w  = (const float*)d_in[9];
  const float* fc_b  = (const float*)d_in[10];
  float* out = (float*)d_out;

  if (ws_size >= WS_NEED){
    hipMemsetAsync(d_ws, 0, FLAGBYTES, stream);
    lstm_pipe2<<<dim3(2*NP), dim3(512), 0, stream>>>(
        x, w_ih0, w_hh0, b_ih0, b_hh0, w_ih1, w_hh1, b_ih1, b_hh1,
        fc_w, fc_b, out, (char*)d_ws);
  } else if (ws_size >= (size_t)131072){
    lstm_fb<1><<<dim3(256), dim3(512), 0, stream>>>(
        x, w_ih0, w_hh0, b_ih0, b_hh0, w_ih1, w_hh1, b_ih1, b_hh1,
        fc_w, fc_b, out, (unsigned short*)d_ws);
  } else {
    lstm_fb<0><<<dim3(256), dim3(512), 0, stream>>>(
        x, w_ih0, w_hh0, b_ih0, b_hh0, w_ih1, w_hh1, b_ih1, b_hh1,
        fc_w, fc_b, out, (unsigned short*)d_ws);
  }
}

// Round 16
// 3141.940 us; speedup vs baseline: 5.8768x; 2.6211x over previous
//
#include <hip/hip_runtime.h>

#define SEQ 1024
#define ISZ 6
#define HSZ 128
#define PRED 50
#define MROW 16
#define HP   136
#define XCH  8
#define TSTEPS (SEQ + PRED)

// d_ws: whh0 pack (131072B) + wih1-kt23 pack (65536B)
#define W0OFF 0
#define W1OFF 65536          // in shorts
#define WS_NEED ((size_t)196608)

using f32x4  = __attribute__((ext_vector_type(4))) float;
using bf16x8 = __attribute__((ext_vector_type(8))) short;

__device__ __forceinline__ short f2bf(float f){
  union { float f; unsigned u; } v; v.f = f;
  unsigned r = v.u + 0x7FFFu + ((v.u >> 16) & 1u);
  return (short)(r >> 16);
}
__device__ __forceinline__ float bf2f(unsigned short us){
  union { unsigned u; float f; } v; v.u = ((unsigned)us) << 16; return v.f;
}
__device__ __forceinline__ float sigf(float x){
  float e = __builtin_amdgcn_exp2f(x * -1.4426950408889634f);
  return __builtin_amdgcn_rcpf(1.0f + e);
}
__device__ __forceinline__ float tanhf_(float x){
  float e = __builtin_amdgcn_exp2f(x * 2.8853900817779268f);
  return 1.0f - 2.0f * __builtin_amdgcn_rcpf(1.0f + e);
}
#define PIN(v) asm volatile("" : "+v"(v))

// Monolith v2 (r11 arithmetic, restructured for overlap):
//  Phase A (everything depending only on t-1 state):
//    x@wih0 + [stream whh0 kt-frags || h1(t-1)@whh1 (LDS) || h0(t-1)@whh0]
//    -> layer0 acts -> h0(t) write -> barrier
//  Phase B: h0(t)@wih1 (kt0,1 regs; kt2,3 streamed) -> layer1 acts -> h1(t)
//    write (double-buffered -> no read/write barrier) -> barrier
//  Cross-block pipelines are dead (r12-15: deadlock / uncached atomics /
//  fence-flush 1GB per dispatch). This attacks the monolith's latency
//  serialization instead: 2 barriers/step, stream latency hidden under
//  2x independent MFMA+LDS work, reg peak ~116 <= the immovable 128 grant.
template<int PRECVT>
__global__
__attribute__((amdgpu_flat_work_group_size(512, 512)))
void lstm_m2(
    const float* __restrict__ x,
    const float* __restrict__ w_ih0, const float* __restrict__ w_hh0,
    const float* __restrict__ b_ih0, const float* __restrict__ b_hh0,
    const float* __restrict__ w_ih1, const float* __restrict__ w_hh1,
    const float* __restrict__ b_ih1, const float* __restrict__ b_hh1,
    const float* __restrict__ fc_w, const float* __restrict__ fc_b,
    float* __restrict__ out, unsigned short* __restrict__ wsb)
{
  __shared__ __align__(16) short s_whh1[65536];     // 131072B swizzled pack
  __shared__ __align__(16) short s_h0[2][MROW*HP];  // 8704B
  __shared__ __align__(16) short s_h1[2][MROW*HP];  // 8704B
  __shared__ __align__(16) short s_x[(XCH+1)*MROW*8]; // 2304B
  __shared__ __align__(16) short s_wih0[512*8];     // 8192B
  __shared__ __align__(16) float s_bias[1024];      // 4096B
  __shared__ float s_fcb[8];
  __shared__ __align__(16) short s_zpad[8];
  // total 163120B <= 163840

  const int tid  = threadIdx.x;
  const int wv   = tid >> 6;
  const int lane = tid & 63;
  const int l15  = lane & 15;
  const int lq   = lane >> 4;
  const int u    = wv*16 + l15;
  const int row0 = blockIdx.x * MROW;
  char* const whh1b = (char*)s_whh1;
  unsigned short* const w0p = wsb + W0OFF;
  unsigned short* const w1p = wsb + W1OFF;

  // ---- init ----
  for (int i = tid; i < 2*MROW*HP; i += 512) (&s_h0[0][0])[i] = 0;
  for (int i = tid; i < 2*MROW*HP; i += 512) (&s_h1[0][0])[i] = 0;
  for (int i = tid; i < (XCH+1)*MROW*8; i += 512) s_x[i] = 0;
  if (tid < 8){ s_zpad[tid] = 0; s_fcb[tid] = (tid < 6) ? fc_b[tid] : 0.f; }
  {
    #pragma unroll
    for (int k = 0; k < 6; k++) s_wih0[tid*8 + k] = f2bf(w_ih0[tid*6 + k]);
    s_wih0[tid*8 + 6] = 0; s_wih0[tid*8 + 7] = 0;
  }
  for (int i = tid; i < 1024; i += 512)
    s_bias[i] = (i < 512) ? (b_ih0[i] + b_hh0[i]) : (b_ih1[i-512] + b_hh1[i-512]);
  // whh1 -> LDS swizzled pack (r11-proven pair)
  for (int i = tid; i < 32768; i += 512){
    const int c = i >> 6, kp = i & 63;
    const unsigned lo = (unsigned short)f2bf(w_hh1[c*128 + 2*kp]);
    const unsigned hi = (unsigned short)f2bf(w_hh1[c*128 + 2*kp + 1]);
    *(unsigned*)(whh1b + ((i*4) ^ ((c & 7) << 4))) = lo | (hi << 16);
  }
  // ws packs (each thread reads only slots it wrote itself)
  if (PRECVT){
    #pragma unroll
    for (int g = 0; g < 4; g++){
      const int c = g*128 + u;
      #pragma unroll
      for (int kt = 0; kt < 4; kt++){
        const float* wp = w_hh0 + c*HSZ + kt*32 + lq*8;
        bf16x8 f;
        #pragma unroll
        for (int i = 0; i < 8; i++) f[i] = f2bf(wp[i]);
        *(bf16x8*)(w0p + (((wv*4 + g)*4 + kt)*64 + lane)*8) = f;
      }
      #pragma unroll
      for (int ktl = 0; ktl < 2; ktl++){
        const float* wp = w_ih1 + c*HSZ + (2 + ktl)*32 + lq*8;
        bf16x8 f;
        #pragma unroll
        for (int i = 0; i < 8; i++) f[i] = f2bf(wp[i]);
        *(bf16x8*)(w1p + (((wv*4 + g)*2 + ktl)*64 + lane)*8) = f;
      }
    }
  }
  // wih1 kt0,1 -> registers (32 VGPRs, PINned)
  bf16x8 wih1f[4][2];
  #pragma unroll
  for (int g = 0; g < 4; g++){
    const int c = g*128 + u;
    #pragma unroll
    for (int kt = 0; kt < 2; kt++){
      const float* wp = w_ih1 + c*HSZ + kt*32 + lq*8;
      bf16x8 f;
      #pragma unroll
      for (int i = 0; i < 8; i++) f[i] = f2bf(wp[i]);
      wih1f[g][kt] = f;
    }
  }

  float c0[4] = {0.f,0.f,0.f,0.f}, c1[4] = {0.f,0.f,0.f,0.f};
  volatile const float* vb = s_bias;
  __syncthreads();

  for (int t = 0; t < TSTEPS; ++t){
    #pragma unroll
    for (int g = 0; g < 4; g++){ PIN(wih1f[g][0]); PIN(wih1f[g][1]); }

    if (t < SEQ && (t & (XCH-1)) == 0){
      for (int i = tid; i < XCH*MROW*ISZ; i += 512){
        const int r = i / (XCH*ISZ), rem = i % (XCH*ISZ);
        const int ts = rem / ISZ, k = rem % ISZ;
        s_x[(ts*MROW + r)*8 + k] =
          f2bf(x[(size_t)(row0 + r)*(SEQ*ISZ) + (size_t)(t + ts)*ISZ + k]);
      }
      __syncthreads();
    }
    const int tt = (t < SEQ) ? (t & (XCH-1)) : XCH;
    const int pb = t & 1, qb = pb ^ 1;
    short* const h0q = &s_h0[qb][0];
    short* const h0p = &s_h0[pb][0];
    short* const h1q = &s_h1[qb][0];
    short* const h1p = &s_h1[pb][0];

    // ================= PHASE A (all t-1-dependent work) =================
    float b0t[4], b1t[4];
    #pragma unroll
    for (int g = 0; g < 4; g++){ b0t[g] = vb[g*128 + u]; b1t[g] = vb[512 + g*128 + u]; }

    const bf16x8 ax = *(const bf16x8*)((lq == 0) ? (s_x + (tt*MROW + l15)*8) : s_zpad);
    f32x4 acc0[4], acc1[4];
    #pragma unroll
    for (int g = 0; g < 4; g++){
      const bf16x8 bw = *(const bf16x8*)((lq == 0) ? (s_wih0 + (g*128 + u)*8) : s_zpad);
      f32x4 ci; ci[0]=b0t[g]; ci[1]=b0t[g]; ci[2]=b0t[g]; ci[3]=b0t[g];
      acc0[g] = __builtin_amdgcn_mfma_f32_16x16x32_bf16(ax, bw, ci, 0, 0, 0);
      acc1[g][0]=b1t[g]; acc1[g][1]=b1t[g]; acc1[g][2]=b1t[g]; acc1[g][3]=b1t[g];
    }
    #pragma unroll
    for (int kt = 0; kt < 4; kt++){
      // issue whh0 stream for this kt (independent of everything below)
      bf16x8 stg[4];
      if (PRECVT){
        #pragma unroll
        for (int g = 0; g < 4; g++)
          stg[g] = *(const bf16x8*)(w0p + (((wv*4 + g)*4 + kt)*64 + lane)*8);
      } else {
        #pragma unroll
        for (int g = 0; g < 4; g++){
          const float* wp = w_hh0 + (g*128 + u)*HSZ + kt*32 + lq*8;
          bf16x8 f;
          #pragma unroll
          for (int i = 0; i < 8; i++) f[i] = f2bf(wp[i]);
          stg[g] = f;
        }
      }
      // layer1 recurrent part: h1(t-1) @ whh1 (LDS B) — hides stream latency
      const bf16x8 a1 = *(const bf16x8*)(h1q + l15*HP + (kt*4 + lq)*8);
      #pragma unroll
      for (int g = 0; g < 4; g++){
        const int c = g*128 + u;
        const bf16x8 b = *(const bf16x8*)(whh1b +
            ((c*256 + (kt*4 + lq)*16) ^ ((u & 7) << 4)));
        acc1[g] = __builtin_amdgcn_mfma_f32_16x16x32_bf16(a1, b, acc1[g], 0, 0, 0);
      }
      // layer0 recurrent part: h0(t-1) @ whh0 (streamed B)
      const bf16x8 a0 = *(const bf16x8*)(h0q + l15*HP + (kt*4 + lq)*8);
      #pragma unroll
      for (int g = 0; g < 4; g++)
        acc0[g] = __builtin_amdgcn_mfma_f32_16x16x32_bf16(a0, stg[g], acc0[g], 0, 0, 0);
    }
    // layer0 activations -> h0(t)
    #pragma unroll
    for (int j = 0; j < 4; j++){
      const float iv = sigf(acc0[0][j]);
      const float fv = sigf(acc0[1][j]);
      const float gv = tanhf_(acc0[2][j]);
      const float ov = sigf(acc0[3][j]);
      c0[j] = fv*c0[j] + iv*gv;
      const float h = ov * tanhf_(c0[j]);
      h0p[(lq*4 + j)*HP + u] = f2bf(h);
    }
    __syncthreads();                       // h0(t) visible

    // ================= PHASE B: h0(t) @ wih1 + layer1 acts ==============
    bf16x8 sB[2][4];                       // streamed wih1 kt2,3 (issued first)
    if (PRECVT){
      #pragma unroll
      for (int ktl = 0; ktl < 2; ktl++)
        #pragma unroll
        for (int g = 0; g < 4; g++)
          sB[ktl][g] = *(const bf16x8*)(w1p + (((wv*4 + g)*2 + ktl)*64 + lane)*8);
    } else {
      #pragma unroll
      for (int ktl = 0; ktl < 2; ktl++)
        #pragma unroll
        for (int g = 0; g < 4; g++){
          const float* wp = w_ih1 + (g*128 + u)*HSZ + (2 + ktl)*32 + lq*8;
          bf16x8 f;
          #pragma unroll
          for (int i = 0; i < 8; i++) f[i] = f2bf(wp[i]);
          sB[ktl][g] = f;
        }
    }
    #pragma unroll
    for (int kt = 0; kt < 2; kt++){        // reg-B part covers stream latency
      const bf16x8 a = *(const bf16x8*)(h0p + l15*HP + (kt*4 + lq)*8);
      #pragma unroll
      for (int g = 0; g < 4; g++)
        acc1[g] = __builtin_amdgcn_mfma_f32_16x16x32_bf16(a, wih1f[g][kt], acc1[g], 0, 0, 0);
    }
    #pragma unroll
    for (int ktl = 0; ktl < 2; ktl++){
      const bf16x8 a = *(const bf16x8*)(h0p + l15*HP + ((2 + ktl)*4 + lq)*8);
      #pragma unroll
      for (int g = 0; g < 4; g++)
        acc1[g] = __builtin_amdgcn_mfma_f32_16x16x32_bf16(a, sB[ktl][g], acc1[g], 0, 0, 0);
    }
    const bool dofc = (t >= SEQ - 1);
    #pragma unroll
    for (int j = 0; j < 4; j++){
      const float iv = sigf(acc1[0][j]);
      const float fv = sigf(acc1[1][j]);
      const float gv = tanhf_(acc1[2][j]);
      const float ov = sigf(acc1[3][j]);
      c1[j] = fv*c1[j] + iv*gv;
      const float h = ov * tanhf_(c1[j]);
      h1p[(lq*4 + j)*HP + u] = f2bf(h);    // dbuf: no read/write hazard
    }
    __syncthreads();                       // h1(t), h0(t) visible for t+1

    // ---- fc head (AR feed), 51 steps ----
    if (dofc){
      if (tid < 96){
        const int r = tid / 6, ii = tid % 6;
        float sacc = 0.f;
        #pragma unroll 4
        for (int kk = 0; kk < 128; kk++)
          sacc += bf2f((unsigned short)h1p[r*HP + kk]) * fc_w[ii*128 + kk];
        const float pred = tanhf_(s_fcb[ii] + sacc);
        s_x[(XCH*MROW + r)*8 + ii] = f2bf(pred);
        if (t >= SEQ)
          out[(size_t)(row0 + r)*(PRED*ISZ) + (size_t)(t - SEQ)*ISZ + ii] = pred;
      }
      __syncthreads();
    }
  }
}

extern "C" void kernel_launch(void* const* d_in, const int* in_sizes, int n_in,
                              void* d_out, int out_size, void* d_ws, size_t ws_size,
                              hipStream_t stream) {
  const float* x     = (const float*)d_in[0];
  const float* w_ih0 = (const float*)d_in[1];
  const float* w_hh0 = (const float*)d_in[2];
  const float* b_ih0 = (const float*)d_in[3];
  const float* b_hh0 = (const float*)d_in[4];
  const float* w_ih1 = (const float*)d_in[5];
  const float* w_hh1 = (const float*)d_in[6];
  const float* b_ih1 = (const float*)d_in[7];
  const float* b_hh1 = (const float*)d_in[8];
  const float* fc_w  = (const float*)d_in[9];
  const float* fc_b  = (const float*)d_in[10];
  float* out = (float*)d_out;

  const int Btot = in_sizes[0] / (SEQ * ISZ);   // 4096
  const int nblk = Btot / MROW;                 // 256

  if (ws_size >= WS_NEED)
    lstm_m2<1><<<dim3(nblk), dim3(512), 0, stream>>>(
        x, w_ih0, w_hh0, b_ih0, b_hh0, w_ih1, w_hh1, b_ih1, b_hh1,
        fc_w, fc_b, out, (unsigned short*)d_ws);
  else
    lstm_m2<0><<<dim3(nblk), dim3(512), 0, stream>>>(
        x, w_ih0, w_hh0, b_ih0, b_hh0, w_ih1, w_hh1, b_ih1, b_hh1,
        fc_w, fc_b, out, (unsigned short*)d_ws);
}